// Round 6
// baseline (453.344 us; speedup 1.0000x reference)
//
#include <hip/hip_runtime.h>
#include <math.h>

#define IR_LEN  2000
#define PFRAME  80
#define NFRAMES 300
#define NBATCH  2
#define NROWS   (NBATCH*NFRAMES)     // 600
#define T_TOTAL (NFRAMES*PFRAME)     // 24000
#define NCOEF   25
#define TWO_PI  6.283185307179586f
#define GS2     66                   // G row stride in complexes (even => 16B-aligned rows)

// ---------------------------------------------------------------------------
// Fused min-phase IR kernel: one block per (batch,frame) row.
//   phase E : E[f] = exp(sum_k c[k] e^{-2pi i f k/4096}), f<=2048, written to
//             LDS at B[f] AND mirrored conj at B[4096-f] (full 4096 spectrum
//             in LDS -> stage 1 is pure aligned b128, no fold reads).
//   stage 1 : G[d][b] = sum_a E[64a+b] w64^{ad}; thread = 4 consecutive b x
//             4 consecutive d, 4 independent rotation chains (R3 shape,
//             VGPR-proven 76). Then G' = G * e^{2pi i b d/4096} -> B[d*66+b].
//   stage 2 : h[64c+d] = (1/4096) Re sum_b G'[d][b] w64^{bc}; thread = 2d x 4c
//             (R5 shape, correctness-proven): c in {cg,cg+8,cg+16,cg+24} from
//             one chain via 8th-root constants, d in {dh, dh+32}.
// LDS: one 33.8 KB union buffer (E then G').
// ---------------------------------------------------------------------------
__global__ __launch_bounds__(256, 4) void minphase_fused(
        const float* __restrict__ mc, float* __restrict__ h_out) {
    __shared__ __align__(16) float2 B[4224];   // max(4096, 64*GS2) = 33.8 KB
    __shared__ float csh[NCOEF];

    const int row = blockIdx.x;
    const int t   = threadIdx.x;
    if (t < NCOEF) csh[t] = mc[row * NCOEF + t];
    __syncthreads();

    // ---------------- phase E (with mirror) ----------------
    for (int f = t; f <= 2048; f += 256) {
        const float ang = -(TWO_PI / 4096.0f) * (float)f;
        float ws, wc; sincosf(ang, &ws, &wc);          // e^{-2pi i f/4096}
        float cr = 1.0f, ci = 0.0f, Cr = 0.0f, Ci = 0.0f;
        #pragma unroll
        for (int k = 0; k < NCOEF; k++) {
            const float cc = csh[k];
            Cr += cc * cr; Ci += cc * ci;
            const float nr = cr * wc - ci * ws;
            const float ni = cr * ws + ci * wc;
            cr = nr; ci = ni;
        }
        const float m = expf(Cr);
        float si, co; sincosf(Ci, &si, &co);
        const float er = m * co, ei = m * si;
        B[f] = make_float2(er, ei);
        if (f > 0 && f < 2048) B[4096 - f] = make_float2(er, -ei);
    }
    __syncthreads();

    // ---------------- stage 1 ----------------
    {
        const int b0 = (t & 15) * 4;
        const int d0 = (t >> 4) * 4;
        float ar[4][4], ai[4][4];                      // [d j][b i]
        #pragma unroll
        for (int j = 0; j < 4; j++)
            #pragma unroll
            for (int i = 0; i < 4; i++) { ar[j][i] = 0.0f; ai[j][i] = 0.0f; }
        float rr[4], ri[4], wr[4], wi[4];
        #pragma unroll
        for (int j = 0; j < 4; j++) {
            float s, c; sincosf((TWO_PI / 64.0f) * (float)(d0 + j), &s, &c);
            wr[j] = c; wi[j] = s; rr[j] = 1.0f; ri[j] = 0.0f;
        }
        #pragma unroll 4
        for (int a = 0; a < 64; a++) {
            const float4 p0 = *(const float4*)&B[a * 64 + b0];      // b0, b0+1
            const float4 p1 = *(const float4*)&B[a * 64 + b0 + 2];  // b0+2, b0+3
            const float er[4] = {p0.x, p0.z, p1.x, p1.z};
            const float ei[4] = {p0.y, p0.w, p1.y, p1.w};
            #pragma unroll
            for (int j = 0; j < 4; j++) {
                #pragma unroll
                for (int i = 0; i < 4; i++) {
                    ar[j][i] += er[i] * rr[j] - ei[i] * ri[j];
                    ai[j][i] += er[i] * ri[j] + ei[i] * rr[j];
                }
                const float nr = rr[j] * wr[j] - ri[j] * wi[j];
                const float ni = rr[j] * wi[j] + ri[j] * wr[j];
                rr[j] = nr; ri[j] = ni;
            }
        }
        __syncthreads();   // all E reads complete before G' overwrites B

        // twiddle-correct G' = G * e^{2pi i b d/4096}, store at stride GS2
        #pragma unroll
        for (int j = 0; j < 4; j++) {
            const int d = d0 + j;
            float ps, pc; sincosf((TWO_PI / 4096.0f) * (float)d, &ps, &pc);
            float cs, cc; sincosf((TWO_PI / 4096.0f) * (float)(b0 * d), &cs, &cc);
            float xr = cc, xi = cs;
            #pragma unroll
            for (int i = 0; i < 4; i++) {
                const float gr = ar[j][i] * xr - ai[j][i] * xi;
                const float gi = ar[j][i] * xi + ai[j][i] * xr;
                B[d * GS2 + b0 + i] = make_float2(gr, gi);
                const float nr = xr * pc - xi * ps;
                const float ni = xr * ps + xi * pc;
                xr = nr; xi = ni;
            }
        }
    }
    __syncthreads();

    // ---------------- stage 2 ----------------
    {
        const int dh = t & 31;                 // d in {dh, dh+32}
        const int cg = t >> 5;                 // c in {cg, cg+8, cg+16, cg+24}
        float sw2, cw2; sincosf((TWO_PI / 64.0f) * (float)cg, &sw2, &cw2);
        float cr_ = 1.0f, ci_ = 0.0f;          // chain w64^{b*cg}
        float acc[4][2] = {{0,0},{0,0},{0,0},{0,0}};   // [c-variant][d-variant]
        const float S2 = 0.70710678118654752f;

        for (int bb = 0; bb < 64; bb += 8) {
            #pragma unroll
            for (int up = 0; up < 4; up++) {
                const int b = bb + 2 * up;
                const float4 q0 = *(const float4*)&B[dh * GS2 + b];
                const float4 q1 = *(const float4*)&B[(dh + 32) * GS2 + b];
                #pragma unroll
                for (int e = 0; e < 2; e++) {
                    const int u = 2 * up + e;          // b mod 8
                    const float gxr = e ? q0.z : q0.x, gxi = e ? q0.w : q0.y;
                    const float gyr = e ? q1.z : q1.x, gyi = e ? q1.w : q1.y;
                    // F1 = chain * e^{2pi i u/8}
                    float f1r, f1i;
                    if      (u == 0) { f1r = cr_;               f1i = ci_;              }
                    else if (u == 1) { f1r = (cr_ - ci_) * S2;  f1i = (cr_ + ci_) * S2; }
                    else if (u == 2) { f1r = -ci_;              f1i = cr_;              }
                    else if (u == 3) { f1r = -(cr_ + ci_) * S2; f1i = (cr_ - ci_) * S2; }
                    else if (u == 4) { f1r = -cr_;              f1i = -ci_;             }
                    else if (u == 5) { f1r = (ci_ - cr_) * S2;  f1i = -(cr_ + ci_) * S2;}
                    else if (u == 6) { f1r = ci_;               f1i = -cr_;             }
                    else             { f1r = (cr_ + ci_) * S2;  f1i = (ci_ - cr_) * S2; }
                    // F2 = chain * i^b ; F3 = F1 * i^b   (b mod 4 == u mod 4)
                    float f2r, f2i, f3r, f3i;
                    const int b4 = u & 3;
                    if      (b4 == 0) { f2r = cr_;  f2i = ci_;  f3r = f1r;  f3i = f1i;  }
                    else if (b4 == 1) { f2r = -ci_; f2i = cr_;  f3r = -f1i; f3i = f1r;  }
                    else if (b4 == 2) { f2r = -cr_; f2i = -ci_; f3r = -f1r; f3i = -f1i; }
                    else              { f2r = ci_;  f2i = -cr_; f3r = f1i;  f3i = -f1r; }
                    acc[0][0] += gxr * cr_ - gxi * ci_;
                    acc[0][1] += gyr * cr_ - gyi * ci_;
                    acc[1][0] += gxr * f1r - gxi * f1i;
                    acc[1][1] += gyr * f1r - gyi * f1i;
                    acc[2][0] += gxr * f2r - gxi * f2i;
                    acc[2][1] += gyr * f2r - gyi * f2i;
                    acc[3][0] += gxr * f3r - gxi * f3i;
                    acc[3][1] += gyr * f3r - gyi * f3i;
                    const float nr = cr_ * cw2 - ci_ * sw2;
                    const float ni = cr_ * sw2 + ci_ * cw2;
                    cr_ = nr; ci_ = ni;
                }
            }
        }
        const float sc = 1.0f / 4096.0f;
        float* ho = h_out + row * IR_LEN;
        #pragma unroll
        for (int v = 0; v < 4; v++) {
            const int c  = cg + 8 * v;
            const int n0 = 64 * c + dh;
            if (n0 < IR_LEN)      ho[n0]      = acc[v][0] * sc;
            if (n0 + 32 < IR_LEN) ho[n0 + 32] = acc[v][1] * sc;
        }
    }
}

// ---------------------------------------------------------------------------
// B: time-varying FIR (unchanged from R4/R5, proven correct, ~5 us).
// ---------------------------------------------------------------------------
__global__ __launch_bounds__(256) void fir_kernel(
        const float* __restrict__ x, const float* __restrict__ h,
        float* __restrict__ y) {
    __shared__ __align__(16) float h0[IR_LEN], h1[IR_LEN];   // 16 KB
    __shared__ __align__(16) float xw[2080];                 // 8.3 KB
    __shared__ __align__(16) float red0[2000], red1[2000];   // 16 KB (25 x 80)

    const int row   = blockIdx.x;              // 0..599
    const int batch = row / NFRAMES;
    const int frame = row - batch * NFRAMES;
    const int t0    = frame * PFRAME;
    const int t     = threadIdx.x;
    const int row1  = (frame + 1 < NFRAMES) ? row + 1 : row;

    const float4* hp0 = (const float4*)(h + (size_t)row  * IR_LEN);
    const float4* hp1 = (const float4*)(h + (size_t)row1 * IR_LEN);
    for (int i = t; i < IR_LEN / 4; i += 256) {
        ((float4*)h0)[i] = hp0[i];
        ((float4*)h1)[i] = hp1[i];
    }
    const float* xb = x + batch * T_TOTAL;
    for (int j = t; j < 2080; j += 256) {
        const int xi = t0 - 1999 + j;
        xw[j] = (xi >= 0 && xi < T_TOTAL) ? xb[xi] : 0.0f;
    }
    __syncthreads();

    if (t < 250) {
        const int o0 = (t % 10) * 8;           // outputs o0..o0+7
        const int kb = (t / 10) * 80;          // taps kb..kb+79
        float s0[8] = {0,0,0,0,0,0,0,0}, s1[8] = {0,0,0,0,0,0,0,0};
        int Bo = 1996 + o0 - kb;               // mult of 4
        float4 w1 = ((const float4*)xw)[Bo / 4 + 1];
        float4 w2 = ((const float4*)xw)[Bo / 4 + 2];
        #pragma unroll 4
        for (int s = 0; s < 20; s++) {
            const float4 w0 = ((const float4*)xw)[Bo / 4];
            const float4 ha = ((const float4*)h0)[kb / 4 + s];
            const float4 hb = ((const float4*)h1)[kb / 4 + s];
            const float wv[12] = {w0.x, w0.y, w0.z, w0.w,
                                  w1.x, w1.y, w1.z, w1.w,
                                  w2.x, w2.y, w2.z, w2.w};
            const float hav[4] = {ha.x, ha.y, ha.z, ha.w};
            const float hbv[4] = {hb.x, hb.y, hb.z, hb.w};
            #pragma unroll
            for (int jo = 0; jo < 8; jo++) {
                #pragma unroll
                for (int jk = 0; jk < 4; jk++) {
                    const float xv = wv[3 + jo - jk];
                    s0[jo] += hav[jk] * xv;
                    s1[jo] += hbv[jk] * xv;
                }
            }
            w2 = w1; w1 = w0; Bo -= 4;
        }
        const int rb = (t / 10) * 80 + o0;     // mult of 4
        *(float4*)&red0[rb]     = make_float4(s0[0], s0[1], s0[2], s0[3]);
        *(float4*)&red0[rb + 4] = make_float4(s0[4], s0[5], s0[6], s0[7]);
        *(float4*)&red1[rb]     = make_float4(s1[0], s1[1], s1[2], s1[3]);
        *(float4*)&red1[rb + 4] = make_float4(s1[4], s1[5], s1[6], s1[7]);
    }
    __syncthreads();

    if (t < PFRAME) {
        float S0 = 0.0f, S1 = 0.0f;
        #pragma unroll
        for (int kc = 0; kc < 25; kc++) {
            S0 += red0[kc * 80 + t];
            S1 += red1[kc * 80 + t];
        }
        const float w = (float)t * (1.0f / (float)PFRAME);
        y[batch * T_TOTAL + t0 + t] = (1.0f - w) * S0 + w * S1;
    }
}

extern "C" void kernel_launch(void* const* d_in, const int* in_sizes, int n_in,
                              void* d_out, int out_size, void* d_ws, size_t ws_size,
                              hipStream_t stream) {
    const float* x  = (const float*)d_in[0];   // (2, 24000)
    const float* mc = (const float*)d_in[1];   // (2, 300, 25)
    float* y    = (float*)d_out;               // (2, 24000)
    float* h_ws = (float*)d_ws;                // 600 * 2000 floats = 4.8 MB

    minphase_fused<<<NROWS, 256, 0, stream>>>(mc, h_ws);
    fir_kernel<<<NROWS, 256, 0, stream>>>(x, h_ws, y);
}

// Round 7
// 118.555 us; speedup vs baseline: 3.8239x; 3.8239x over previous
//
#include <hip/hip_runtime.h>
#include <math.h>

#define IR_LEN  2000
#define PFRAME  80
#define NFRAMES 300
#define NBATCH  2
#define NROWS   (NBATCH*NFRAMES)     // 600
#define T_TOTAL (NFRAMES*PFRAME)     // 24000
#define NCOEF   25
#define TWO_PI  6.283185307179586f
#define GS      68                   // G row stride in floats (16B-aligned rows)

// ---------------------------------------------------------------------------
// Fused min-phase IR kernel: one block per (batch,frame) row. 600 blocks.
//   phase E : E[f] = exp(sum_k c[k] e^{-2pi i f k/4096}), f<=2048, written
//             SoA to LDS with conjugate mirror at 4096-f (full spectrum ->
//             stage 1 is pure aligned b128 reads, 2-way conflicts only).
//   stage 1 : G[b][d] = sum_a E[64a+b] w64^{ad}; thread = 4 consecutive b x
//             4 consecutive d with 4 independent rotation chains (R3 shape,
//             VGPR-proven 76). Then G' = G * e^{2pi i b d/4096} -> Gr/Gi.
//   stage 2 : h[64c+d] = (1/4096) Re sum_b G'[b][d] w64^{bc}; thread =
//             (2 consecutive d, cg): c in {cg, cg+8, cg+16, cg+24} from one
//             rotation chain x constant 8th-roots (R3 STEP2, proven).
// LDS: 34.8 KB union buffer (E SoA 8192 floats, then G SoA 8704 floats).
// NO register-capping launch bounds — R6 showed capping spills (543 MB HBM).
// ---------------------------------------------------------------------------
__global__ __launch_bounds__(256) void minphase_fused(
        const float* __restrict__ mc, float* __restrict__ h_out) {
    __shared__ __align__(16) float U[8704];    // 34.8 KB union
    __shared__ float csh[NCOEF];
    float* const EHr = U;                      // [4096]
    float* const EHi = U + 4096;               // [4096]
    float* const Gr  = U;                      // [64*GS] = 4352
    float* const Gi  = U + 4352;               // [64*GS] = 4352

    const int row = blockIdx.x;
    const int t   = threadIdx.x;
    if (t < NCOEF) csh[t] = mc[row * NCOEF + t];
    __syncthreads();

    // ---------------- phase E (with conjugate mirror) ----------------
    for (int f = t; f <= 2048; f += 256) {
        const float ang = -(TWO_PI / 4096.0f) * (float)f;
        float ws, wc; sincosf(ang, &ws, &wc);          // e^{-2pi i f/4096}
        float cr = 1.0f, ci = 0.0f, Cr = 0.0f, Ci = 0.0f;
        #pragma unroll
        for (int k = 0; k < NCOEF; k++) {
            const float cc = csh[k];
            Cr += cc * cr; Ci += cc * ci;
            const float nr = cr * wc - ci * ws;
            const float ni = cr * ws + ci * wc;
            cr = nr; ci = ni;
        }
        const float m = expf(Cr);
        float si, co; sincosf(Ci, &si, &co);
        const float er = m * co, ei = m * si;
        EHr[f] = er; EHi[f] = ei;
        if (f > 0 && f < 2048) { EHr[4096 - f] = er; EHi[4096 - f] = -ei; }
    }
    __syncthreads();

    // ---------------- stage 1 (R3 shape: 4b x 4d, 4 chains) ----------------
    {
        const int b0 = (t & 15) * 4;
        const int d0 = (t >> 4) * 4;
        float ar[4][4], ai[4][4];                      // [d j][b i]
        #pragma unroll
        for (int j = 0; j < 4; j++)
            #pragma unroll
            for (int i = 0; i < 4; i++) { ar[j][i] = 0.0f; ai[j][i] = 0.0f; }
        float rr[4], ri[4], wr[4], wi[4];
        #pragma unroll
        for (int j = 0; j < 4; j++) {
            float s, c; sincosf((TWO_PI / 64.0f) * (float)(d0 + j), &s, &c);
            wr[j] = c; wi[j] = s; rr[j] = 1.0f; ri[j] = 0.0f;
        }
        #pragma unroll 4
        for (int a = 0; a < 64; a++) {
            const float4 vr = *(const float4*)&EHr[a * 64 + b0];
            const float4 vi = *(const float4*)&EHi[a * 64 + b0];
            const float er[4] = {vr.x, vr.y, vr.z, vr.w};
            const float ei[4] = {vi.x, vi.y, vi.z, vi.w};
            #pragma unroll
            for (int j = 0; j < 4; j++) {
                #pragma unroll
                for (int i = 0; i < 4; i++) {
                    ar[j][i] += er[i] * rr[j] - ei[i] * ri[j];
                    ai[j][i] += er[i] * ri[j] + ei[i] * rr[j];
                }
                const float nr = rr[j] * wr[j] - ri[j] * wi[j];
                const float ni = rr[j] * wi[j] + ri[j] * wr[j];
                rr[j] = nr; ri[j] = ni;
            }
        }
        __syncthreads();   // ALL E reads complete before G' overwrites U

        // twiddle-correct and write G'[b][d] (float4 rows, R3 exact)
        #pragma unroll
        for (int i = 0; i < 4; i++) {
            const int b = b0 + i;
            float orv[4], oiv[4];
            #pragma unroll
            for (int j = 0; j < 4; j++) {
                float s, c;
                sincosf((TWO_PI / 4096.0f) * (float)(b * (d0 + j)), &s, &c);
                orv[j] = ar[j][i] * c - ai[j][i] * s;
                oiv[j] = ar[j][i] * s + ai[j][i] * c;
            }
            *(float4*)&Gr[b * GS + d0] = make_float4(orv[0], orv[1], orv[2], orv[3]);
            *(float4*)&Gi[b * GS + d0] = make_float4(oiv[0], oiv[1], oiv[2], oiv[3]);
        }
    }
    __syncthreads();

    // ---------------- stage 2 (R3 STEP2, proven) ----------------
    {
        const int dl = (t & 31) * 2;
        const int cg = t >> 5;                     // 0..7
        float swi_, swr_; sincosf((TWO_PI / 64.0f) * (float)cg, &swi_, &swr_);
        const float swr = swr_, swi = swi_;        // step e^{2pi i cg/64}
        float rr = 1.0f, ri = 0.0f;
        float acc00 = 0, acc01 = 0, acc10 = 0, acc11 = 0;
        float acc20 = 0, acc21 = 0, acc30 = 0, acc31 = 0;
        int bb = 0;

#define S2C 0.70710678118654752f
#define STEP2(f8r, f8i, f16r, f16i, f24r, f24i)                                \
        {                                                                      \
            const float2 g_r = *(const float2*)&Gr[bb * GS + dl];              \
            const float2 g_i = *(const float2*)&Gi[bb * GS + dl];              \
            acc00 += g_r.x * rr - g_i.x * ri;                                  \
            acc01 += g_r.y * rr - g_i.y * ri;                                  \
            { const float tr = rr*(f8r) - ri*(f8i), ti = rr*(f8i) + ri*(f8r);  \
              acc10 += g_r.x * tr - g_i.x * ti;                                \
              acc11 += g_r.y * tr - g_i.y * ti; }                              \
            { const float tr = rr*(f16r) - ri*(f16i), ti = rr*(f16i) + ri*(f16r); \
              acc20 += g_r.x * tr - g_i.x * ti;                                \
              acc21 += g_r.y * tr - g_i.y * ti; }                              \
            { const float tr = rr*(f24r) - ri*(f24i), ti = rr*(f24i) + ri*(f24r); \
              acc30 += g_r.x * tr - g_i.x * ti;                                \
              acc31 += g_r.y * tr - g_i.y * ti; }                              \
            { const float nr = rr * swr - ri * swi;                            \
              const float ni = rr * swi + ri * swr;                            \
              rr = nr; ri = ni; }                                              \
            bb++;                                                              \
        }

        for (int grp = 0; grp < 8; grp++) {
            STEP2( 1.0f, 0.0f,   1.0f, 0.0f,   1.0f, 0.0f)
            STEP2( S2C,  S2C,    0.0f, 1.0f,  -S2C,  S2C)
            STEP2( 0.0f, 1.0f,  -1.0f, 0.0f,   0.0f,-1.0f)
            STEP2(-S2C,  S2C,    0.0f,-1.0f,   S2C,  S2C)
            STEP2(-1.0f, 0.0f,   1.0f, 0.0f,  -1.0f, 0.0f)
            STEP2(-S2C, -S2C,    0.0f, 1.0f,   S2C, -S2C)
            STEP2( 0.0f,-1.0f,  -1.0f, 0.0f,   0.0f, 1.0f)
            STEP2( S2C, -S2C,    0.0f,-1.0f,  -S2C, -S2C)
        }
#undef STEP2

        const float sc = 1.0f / 4096.0f;
        float* ho = h_out + row * IR_LEN;
        const float av[4][2] = {{acc00, acc01}, {acc10, acc11},
                                {acc20, acc21}, {acc30, acc31}};
        #pragma unroll
        for (int v = 0; v < 4; v++) {
            const int c = cg + 8 * v;
            #pragma unroll
            for (int e = 0; e < 2; e++) {
                const int n = 64 * c + dl + e;
                if (n < IR_LEN) ho[n] = av[v][e] * sc;
            }
        }
    }
}

// ---------------------------------------------------------------------------
// B: time-varying FIR (unchanged from R4/R5, proven correct, ~5 us).
// ---------------------------------------------------------------------------
__global__ __launch_bounds__(256) void fir_kernel(
        const float* __restrict__ x, const float* __restrict__ h,
        float* __restrict__ y) {
    __shared__ __align__(16) float h0[IR_LEN], h1[IR_LEN];   // 16 KB
    __shared__ __align__(16) float xw[2080];                 // 8.3 KB
    __shared__ __align__(16) float red0[2000], red1[2000];   // 16 KB (25 x 80)

    const int row   = blockIdx.x;              // 0..599
    const int batch = row / NFRAMES;
    const int frame = row - batch * NFRAMES;
    const int t0    = frame * PFRAME;
    const int t     = threadIdx.x;
    const int row1  = (frame + 1 < NFRAMES) ? row + 1 : row;

    const float4* hp0 = (const float4*)(h + (size_t)row  * IR_LEN);
    const float4* hp1 = (const float4*)(h + (size_t)row1 * IR_LEN);
    for (int i = t; i < IR_LEN / 4; i += 256) {
        ((float4*)h0)[i] = hp0[i];
        ((float4*)h1)[i] = hp1[i];
    }
    const float* xb = x + batch * T_TOTAL;
    for (int j = t; j < 2080; j += 256) {
        const int xi = t0 - 1999 + j;
        xw[j] = (xi >= 0 && xi < T_TOTAL) ? xb[xi] : 0.0f;
    }
    __syncthreads();

    if (t < 250) {
        const int o0 = (t % 10) * 8;           // outputs o0..o0+7
        const int kb = (t / 10) * 80;          // taps kb..kb+79
        float s0[8] = {0,0,0,0,0,0,0,0}, s1[8] = {0,0,0,0,0,0,0,0};
        int Bo = 1996 + o0 - kb;               // mult of 4
        float4 w1 = ((const float4*)xw)[Bo / 4 + 1];
        float4 w2 = ((const float4*)xw)[Bo / 4 + 2];
        #pragma unroll 4
        for (int s = 0; s < 20; s++) {
            const float4 w0 = ((const float4*)xw)[Bo / 4];
            const float4 ha = ((const float4*)h0)[kb / 4 + s];
            const float4 hb = ((const float4*)h1)[kb / 4 + s];
            const float wv[12] = {w0.x, w0.y, w0.z, w0.w,
                                  w1.x, w1.y, w1.z, w1.w,
                                  w2.x, w2.y, w2.z, w2.w};
            const float hav[4] = {ha.x, ha.y, ha.z, ha.w};
            const float hbv[4] = {hb.x, hb.y, hb.z, hb.w};
            #pragma unroll
            for (int jo = 0; jo < 8; jo++) {
                #pragma unroll
                for (int jk = 0; jk < 4; jk++) {
                    const float xv = wv[3 + jo - jk];
                    s0[jo] += hav[jk] * xv;
                    s1[jo] += hbv[jk] * xv;
                }
            }
            w2 = w1; w1 = w0; Bo -= 4;
        }
        const int rb = (t / 10) * 80 + o0;     // mult of 4
        *(float4*)&red0[rb]     = make_float4(s0[0], s0[1], s0[2], s0[3]);
        *(float4*)&red0[rb + 4] = make_float4(s0[4], s0[5], s0[6], s0[7]);
        *(float4*)&red1[rb]     = make_float4(s1[0], s1[1], s1[2], s1[3]);
        *(float4*)&red1[rb + 4] = make_float4(s1[4], s1[5], s1[6], s1[7]);
    }
    __syncthreads();

    if (t < PFRAME) {
        float S0 = 0.0f, S1 = 0.0f;
        #pragma unroll
        for (int kc = 0; kc < 25; kc++) {
            S0 += red0[kc * 80 + t];
            S1 += red1[kc * 80 + t];
        }
        const float w = (float)t * (1.0f / (float)PFRAME);
        y[batch * T_TOTAL + t0 + t] = (1.0f - w) * S0 + w * S1;
    }
}

extern "C" void kernel_launch(void* const* d_in, const int* in_sizes, int n_in,
                              void* d_out, int out_size, void* d_ws, size_t ws_size,
                              hipStream_t stream) {
    const float* x  = (const float*)d_in[0];   // (2, 24000)
    const float* mc = (const float*)d_in[1];   // (2, 300, 25)
    float* y    = (float*)d_out;               // (2, 24000)
    float* h_ws = (float*)d_ws;                // 600 * 2000 floats = 4.8 MB

    minphase_fused<<<NROWS, 256, 0, stream>>>(mc, h_ws);
    fir_kernel<<<NROWS, 256, 0, stream>>>(x, h_ws, y);
}

// Round 8
// 112.033 us; speedup vs baseline: 4.0465x; 1.0582x over previous
//
#include <hip/hip_runtime.h>
#include <math.h>

#define IR_LEN  2000
#define PFRAME  80
#define NFRAMES 300
#define NBATCH  2
#define NROWS   (NBATCH*NFRAMES)     // 600
#define T_TOTAL (NFRAMES*PFRAME)     // 24000
#define NCOEF   25
#define TWO_PI  6.283185307179586f
#define GS      68                   // G row stride in floats (16B-aligned rows)
#define XWN     2160                 // x window floats per block

// ---------------------------------------------------------------------------
// Fully fused kernel: one block per (batch,frame) row. 600 blocks, 256 thr.
//   phase E : E[f] = exp(sum_k c[k] e^{-2pi i f k/4096}) -> LDS (SoA, full
//             4096 spectrum via conjugate mirror).
//   stage 1 : G[b][d] = sum_a E[64a+b] w64^{ad} (4b x 4d tile, 4 rotation
//             chains — R3/R7 proven, VGPR-lean), then G' = G e^{2pi i bd/4096}.
//   stage 2 : h[64c+d] = (1/4096) Re sum_b G'[b][d] w64^{bc} (R3 STEP2) ->
//             h kept in LDS (NO global h traffic).
//   FIR     : z[t] = <h, xwin(t)> for t in [t0-80, t0+80) — 160 outputs, one
//             convolution (R4's sliding-window 8-out x 4-tap register tile).
//   epilogue: y[t0-80+o] += w(o) * z[o], tent w(o) = min(o,160-o)/80;
//             frame 0 skips o<80; frame 299 uses w=1 for o>=80 (clamped
//             h_next). Two writers per output -> atomicAdd; y zeroed by
//             hipMemsetAsync before launch (graph-capturable).
// LDS: one 34.8 KB union buffer re-used across phases.
// ---------------------------------------------------------------------------
__global__ __launch_bounds__(256) void minphase_fir_fused(
        const float* __restrict__ mc, const float* __restrict__ x,
        float* __restrict__ y) {
    __shared__ __align__(16) float U[8704];    // 34.8 KB union
    __shared__ float csh[NCOEF];
    float* const EHr = U;                      // [4096]      (phase E)
    float* const EHi = U + 4096;               // [4096]
    float* const Gr  = U;                      // [64*GS]     (stage 1/2)
    float* const Gi  = U + 4352;               // [64*GS]
    float* const hU  = U;                      // [2000]      (FIR phase)
    float* const xw  = U + 2048;               // [2160]
    float* const red = U + 4224;               // [12*160 = 1920]

    const int row   = blockIdx.x;
    const int batch = row / NFRAMES;
    const int frame = row - batch * NFRAMES;
    const int t0    = frame * PFRAME;
    const int t     = threadIdx.x;

    if (t < NCOEF) csh[t] = mc[row * NCOEF + t];
    __syncthreads();

    // ---------------- phase E (with conjugate mirror) ----------------
    for (int f = t; f <= 2048; f += 256) {
        const float ang = -(TWO_PI / 4096.0f) * (float)f;
        float ws, wc; sincosf(ang, &ws, &wc);          // e^{-2pi i f/4096}
        float cr = 1.0f, ci = 0.0f, Cr = 0.0f, Ci = 0.0f;
        #pragma unroll
        for (int k = 0; k < NCOEF; k++) {
            const float cc = csh[k];
            Cr += cc * cr; Ci += cc * ci;
            const float nr = cr * wc - ci * ws;
            const float ni = cr * ws + ci * wc;
            cr = nr; ci = ni;
        }
        const float m = expf(Cr);
        float si, co; sincosf(Ci, &si, &co);
        const float er = m * co, ei = m * si;
        EHr[f] = er; EHi[f] = ei;
        if (f > 0 && f < 2048) { EHr[4096 - f] = er; EHi[4096 - f] = -ei; }
    }
    __syncthreads();

    // ---------------- stage 1 (4b x 4d, 4 chains) ----------------
    {
        const int b0 = (t & 15) * 4;
        const int d0 = (t >> 4) * 4;
        float ar[4][4], ai[4][4];                      // [d j][b i]
        #pragma unroll
        for (int j = 0; j < 4; j++)
            #pragma unroll
            for (int i = 0; i < 4; i++) { ar[j][i] = 0.0f; ai[j][i] = 0.0f; }
        float rr[4], ri[4], wr[4], wi[4];
        #pragma unroll
        for (int j = 0; j < 4; j++) {
            float s, c; sincosf((TWO_PI / 64.0f) * (float)(d0 + j), &s, &c);
            wr[j] = c; wi[j] = s; rr[j] = 1.0f; ri[j] = 0.0f;
        }
        #pragma unroll 4
        for (int a = 0; a < 64; a++) {
            const float4 vr = *(const float4*)&EHr[a * 64 + b0];
            const float4 vi = *(const float4*)&EHi[a * 64 + b0];
            const float er[4] = {vr.x, vr.y, vr.z, vr.w};
            const float ei[4] = {vi.x, vi.y, vi.z, vi.w};
            #pragma unroll
            for (int j = 0; j < 4; j++) {
                #pragma unroll
                for (int i = 0; i < 4; i++) {
                    ar[j][i] += er[i] * rr[j] - ei[i] * ri[j];
                    ai[j][i] += er[i] * ri[j] + ei[i] * rr[j];
                }
                const float nr = rr[j] * wr[j] - ri[j] * wi[j];
                const float ni = rr[j] * wi[j] + ri[j] * wr[j];
                rr[j] = nr; ri[j] = ni;
            }
        }
        __syncthreads();   // ALL E reads complete before G' overwrites U

        #pragma unroll
        for (int i = 0; i < 4; i++) {
            const int b = b0 + i;
            float orv[4], oiv[4];
            #pragma unroll
            for (int j = 0; j < 4; j++) {
                float s, c;
                sincosf((TWO_PI / 4096.0f) * (float)(b * (d0 + j)), &s, &c);
                orv[j] = ar[j][i] * c - ai[j][i] * s;
                oiv[j] = ar[j][i] * s + ai[j][i] * c;
            }
            *(float4*)&Gr[b * GS + d0] = make_float4(orv[0], orv[1], orv[2], orv[3]);
            *(float4*)&Gi[b * GS + d0] = make_float4(oiv[0], oiv[1], oiv[2], oiv[3]);
        }
    }
    __syncthreads();

    // ---------------- stage 2 (STEP2, proven) -> h in registers ----------
    float hv[4][2];                            // [c-variant][d pair elem]
    int   dl_, cg_;
    {
        const int dl = (t & 31) * 2;
        const int cg = t >> 5;                     // 0..7
        dl_ = dl; cg_ = cg;
        float swi_, swr_; sincosf((TWO_PI / 64.0f) * (float)cg, &swi_, &swr_);
        const float swr = swr_, swi = swi_;        // step e^{2pi i cg/64}
        float rr = 1.0f, ri = 0.0f;
        float acc00 = 0, acc01 = 0, acc10 = 0, acc11 = 0;
        float acc20 = 0, acc21 = 0, acc30 = 0, acc31 = 0;
        int bb = 0;

#define S2C 0.70710678118654752f
#define STEP2(f8r, f8i, f16r, f16i, f24r, f24i)                                \
        {                                                                      \
            const float2 g_r = *(const float2*)&Gr[bb * GS + dl];              \
            const float2 g_i = *(const float2*)&Gi[bb * GS + dl];              \
            acc00 += g_r.x * rr - g_i.x * ri;                                  \
            acc01 += g_r.y * rr - g_i.y * ri;                                  \
            { const float tr = rr*(f8r) - ri*(f8i), ti = rr*(f8i) + ri*(f8r);  \
              acc10 += g_r.x * tr - g_i.x * ti;                                \
              acc11 += g_r.y * tr - g_i.y * ti; }                              \
            { const float tr = rr*(f16r) - ri*(f16i), ti = rr*(f16i) + ri*(f16r); \
              acc20 += g_r.x * tr - g_i.x * ti;                                \
              acc21 += g_r.y * tr - g_i.y * ti; }                              \
            { const float tr = rr*(f24r) - ri*(f24i), ti = rr*(f24i) + ri*(f24r); \
              acc30 += g_r.x * tr - g_i.x * ti;                                \
              acc31 += g_r.y * tr - g_i.y * ti; }                              \
            { const float nr = rr * swr - ri * swi;                            \
              const float ni = rr * swi + ri * swr;                            \
              rr = nr; ri = ni; }                                              \
            bb++;                                                              \
        }

        for (int grp = 0; grp < 8; grp++) {
            STEP2( 1.0f, 0.0f,   1.0f, 0.0f,   1.0f, 0.0f)
            STEP2( S2C,  S2C,    0.0f, 1.0f,  -S2C,  S2C)
            STEP2( 0.0f, 1.0f,  -1.0f, 0.0f,   0.0f,-1.0f)
            STEP2(-S2C,  S2C,    0.0f,-1.0f,   S2C,  S2C)
            STEP2(-1.0f, 0.0f,   1.0f, 0.0f,  -1.0f, 0.0f)
            STEP2(-S2C, -S2C,    0.0f, 1.0f,   S2C, -S2C)
            STEP2( 0.0f,-1.0f,  -1.0f, 0.0f,   0.0f, 1.0f)
            STEP2( S2C, -S2C,    0.0f,-1.0f,  -S2C, -S2C)
        }
#undef STEP2
        const float sc = 1.0f / 4096.0f;
        hv[0][0] = acc00 * sc; hv[0][1] = acc01 * sc;
        hv[1][0] = acc10 * sc; hv[1][1] = acc11 * sc;
        hv[2][0] = acc20 * sc; hv[2][1] = acc21 * sc;
        hv[3][0] = acc30 * sc; hv[3][1] = acc31 * sc;
    }
    __syncthreads();   // all G reads done; U is free

    // ---------------- h -> LDS, x window -> LDS ----------------
    #pragma unroll
    for (int v = 0; v < 4; v++) {
        const int c = cg_ + 8 * v;
        const int n = 64 * c + dl_;
        if (n < IR_LEN)     hU[n]     = hv[v][0];
        if (n + 1 < IR_LEN) hU[n + 1] = hv[v][1];
    }
    const float* xb = x + batch * T_TOTAL;
    for (int j = t; j < XWN; j += 256) {
        const int xi = t0 - 2079 + j;
        xw[j] = (xi >= 0 && xi < T_TOTAL) ? xb[xi] : 0.0f;
    }
    __syncthreads();

    // ---------------- FIR: z[o] for o in [0,160), t_out = t0 - 80 + o ------
    // thread: og = t%20 -> outputs o0 = 8*og..+7 ; kc = t/20 -> tap chunk
    if (t < 240) {
        const int o0 = (t % 20) * 8;
        const int kc = t / 20;                 // 0..11
        const int kb = kc * 168;
        const int ns = (kc == 11) ? 38 : 42;   // 11*168=1848, +152 = 2000
        float s0[8] = {0,0,0,0,0,0,0,0};
        int Bo = o0 + 1996 - kb;               // mult of 4, >= 0
        float4 w1 = *(const float4*)&xw[Bo + 4];
        float4 w2 = *(const float4*)&xw[Bo + 8];
        for (int s = 0; s < ns; s++) {
            const float4 w0 = *(const float4*)&xw[Bo];
            const float4 ha = *(const float4*)&hU[kb + 4 * s];
            const float wv[12] = {w0.x, w0.y, w0.z, w0.w,
                                  w1.x, w1.y, w1.z, w1.w,
                                  w2.x, w2.y, w2.z, w2.w};
            const float hav[4] = {ha.x, ha.y, ha.z, ha.w};
            #pragma unroll
            for (int jo = 0; jo < 8; jo++) {
                #pragma unroll
                for (int jk = 0; jk < 4; jk++) {
                    s0[jo] += hav[jk] * wv[3 + jo - jk];
                }
            }
            w2 = w1; w1 = w0; Bo -= 4;
        }
        const int rb = kc * 160 + o0;          // mult of 8
        *(float4*)&red[rb]     = make_float4(s0[0], s0[1], s0[2], s0[3]);
        *(float4*)&red[rb + 4] = make_float4(s0[4], s0[5], s0[6], s0[7]);
    }
    __syncthreads();

    // ---------------- epilogue: tent-weighted atomic scatter ----------------
    if (t < 160) {
        float z = 0.0f;
        #pragma unroll
        for (int kc = 0; kc < 12; kc++) z += red[kc * 160 + t];
        const int o = t;
        const int tout = t0 - PFRAME + o;
        float wgt = (o < PFRAME) ? (float)o * (1.0f / PFRAME)
                                 : (float)(160 - o) * (1.0f / PFRAME);
        if (frame == NFRAMES - 1 && o >= PFRAME) wgt = 1.0f;  // clamped h_next
        if (tout >= 0) {                       // frame 0 has no previous frame
            atomicAdd(&y[batch * T_TOTAL + tout], wgt * z);
        }
    }
}

extern "C" void kernel_launch(void* const* d_in, const int* in_sizes, int n_in,
                              void* d_out, int out_size, void* d_ws, size_t ws_size,
                              hipStream_t stream) {
    const float* x  = (const float*)d_in[0];   // (2, 24000)
    const float* mc = (const float*)d_in[1];   // (2, 300, 25)
    float* y = (float*)d_out;                  // (2, 24000)

    hipMemsetAsync(y, 0, (size_t)out_size * sizeof(float), stream);
    minphase_fir_fused<<<NROWS, 256, 0, stream>>>(mc, x, y);
}

// Round 9
// 111.690 us; speedup vs baseline: 4.0589x; 1.0031x over previous
//
#include <hip/hip_runtime.h>
#include <math.h>

#define IR_LEN  2000
#define PFRAME  80
#define NFRAMES 300
#define NBATCH  2
#define NROWS   (NBATCH*NFRAMES)     // 600
#define T_TOTAL (NFRAMES*PFRAME)     // 24000
#define NCOEF   25
#define TWO_PI  6.283185307179586f
#define GS      68                   // G row stride in floats (16B-aligned rows)
#define XWN     2160                 // logical x-window floats per block
#define XWPAD   2432                 // physical (4-float pad per 32): 2160+4*68

// padded xw addressing: breaks mod-32 bank aliasing of the FIR window reads.
// All read/write offsets are multiples of 4 within a 32-block, so a b128
// never straddles a pad.
#define XPHYS(B) ((B) + (((B) >> 5) << 2))

// ---------------------------------------------------------------------------
// Fully fused kernel: one block per (batch,frame) row. 600 blocks, 256 thr.
//   stage x : x window -> LDS (padded layout), issued FIRST so the global
//             load latency hides under E/stage-1 compute.
//   phase E : E[f] = exp(sum_k c[k] e^{-2pi i f k/4096}) -> LDS SoA with
//             conjugate mirror (full 4096 spectrum). Unrolled x4 for ILP.
//   stage 1 : G[b][d] = sum_a E[64a+b] w64^{ad} (4b x 4d tile, 4 rotation
//             chains — VGPR-lean, R3/R7 proven), then G' = G e^{2pi i bd/4096}.
//   stage 2 : h[64c+d] = (1/4096) Re sum_b G'[b][d] w64^{bc} (STEP2, proven)
//             -> h kept in LDS (no global h traffic).
//   FIR     : z[o] = <h, xwin(t0-80+o)>, o in [0,160) — sliding-window
//             8-out x 4-tap register tile; partials to red slab (stride 168).
//   epilogue: y[t0-80+o] += w(o) * z[o], tent w(o); atomicAdd (y pre-zeroed
//             by hipMemsetAsync).
// LDS: 34.8 KB union (E | G | h+red) + 9.7 KB padded xw + csh = ~44.6 KB
//      -> 3 blocks/CU capacity >= grid's 2.34 blocks/CU. No reg-capping
//      launch bounds (R6: capping spills).
// ---------------------------------------------------------------------------
__global__ __launch_bounds__(256) void minphase_fir_fused(
        const float* __restrict__ mc, const float* __restrict__ x,
        float* __restrict__ y) {
    __shared__ __align__(16) float U[8704];    // 34.8 KB union
    __shared__ __align__(16) float xws[XWPAD]; // 9.7 KB padded x window
    __shared__ float csh[NCOEF];
    float* const EHr = U;                      // [4096]      (phase E)
    float* const EHi = U + 4096;               // [4096]
    float* const Gr  = U;                      // [64*GS]     (stages 1/2)
    float* const Gi  = U + 4352;               // [64*GS]
    float* const hU  = U;                      // [2000]      (FIR phase)
    float* const red = U + 4224;               // [12 rows, stride 168]

    const int row   = blockIdx.x;
    const int batch = row / NFRAMES;
    const int frame = row - batch * NFRAMES;
    const int t0    = frame * PFRAME;
    const int t     = threadIdx.x;

    if (t < NCOEF) csh[t] = mc[row * NCOEF + t];

    // ---------------- stage x: pre-stage x window (padded) ----------------
    {
        const float* xb = x + batch * T_TOTAL;
        for (int j = t; j < XWN; j += 256) {
            const int xi = t0 - 2079 + j;
            const float v = (xi >= 0 && xi < T_TOTAL) ? xb[xi] : 0.0f;
            xws[XPHYS(j)] = v;
        }
    }
    __syncthreads();

    // ---------------- phase E (conjugate mirror, unrolled for ILP) --------
    {
        #pragma unroll 4
        for (int ii = 0; ii < 8; ii++) {
            const int f = t + 256 * ii;                // 0..2047
            const float ang = -(TWO_PI / 4096.0f) * (float)f;
            float ws, wc; sincosf(ang, &ws, &wc);      // e^{-2pi i f/4096}
            float cr = 1.0f, ci = 0.0f, Cr = 0.0f, Ci = 0.0f;
            #pragma unroll
            for (int k = 0; k < NCOEF; k++) {
                const float cc = csh[k];
                Cr += cc * cr; Ci += cc * ci;
                const float nr = cr * wc - ci * ws;
                const float ni = cr * ws + ci * wc;
                cr = nr; ci = ni;
            }
            const float m = expf(Cr);
            float si, co; sincosf(Ci, &si, &co);
            const float er = m * co, ei = m * si;
            EHr[f] = er; EHi[f] = ei;
            if (f > 0) { EHr[4096 - f] = er; EHi[4096 - f] = -ei; }
        }
        if (t == 0) {                                  // f = 2048
            float Cr = 0.0f, Ci = 0.0f;
            float cr = 1.0f, ci = 0.0f;
            #pragma unroll
            for (int k = 0; k < NCOEF; k++) {
                Cr += csh[k] * cr; Ci += csh[k] * ci;
                cr = -cr; ci = -ci;                    // e^{-i pi k} = (-1)^k
            }
            const float m = expf(Cr);
            float si, co; sincosf(Ci, &si, &co);
            EHr[2048] = m * co; EHi[2048] = m * si;
        }
    }
    __syncthreads();

    // ---------------- stage 1 (4b x 4d, 4 chains) ----------------
    {
        const int b0 = (t & 15) * 4;
        const int d0 = (t >> 4) * 4;
        float ar[4][4], ai[4][4];                      // [d j][b i]
        #pragma unroll
        for (int j = 0; j < 4; j++)
            #pragma unroll
            for (int i = 0; i < 4; i++) { ar[j][i] = 0.0f; ai[j][i] = 0.0f; }
        float rr[4], ri[4], wr[4], wi[4];
        #pragma unroll
        for (int j = 0; j < 4; j++) {
            float s, c; sincosf((TWO_PI / 64.0f) * (float)(d0 + j), &s, &c);
            wr[j] = c; wi[j] = s; rr[j] = 1.0f; ri[j] = 0.0f;
        }
        #pragma unroll 4
        for (int a = 0; a < 64; a++) {
            const float4 vr = *(const float4*)&EHr[a * 64 + b0];
            const float4 vi = *(const float4*)&EHi[a * 64 + b0];
            const float er[4] = {vr.x, vr.y, vr.z, vr.w};
            const float ei[4] = {vi.x, vi.y, vi.z, vi.w};
            #pragma unroll
            for (int j = 0; j < 4; j++) {
                #pragma unroll
                for (int i = 0; i < 4; i++) {
                    ar[j][i] += er[i] * rr[j] - ei[i] * ri[j];
                    ai[j][i] += er[i] * ri[j] + ei[i] * rr[j];
                }
                const float nr = rr[j] * wr[j] - ri[j] * wi[j];
                const float ni = rr[j] * wi[j] + ri[j] * wr[j];
                rr[j] = nr; ri[j] = ni;
            }
        }
        __syncthreads();   // ALL E reads complete before G' overwrites U

        #pragma unroll
        for (int i = 0; i < 4; i++) {
            const int b = b0 + i;
            float orv[4], oiv[4];
            #pragma unroll
            for (int j = 0; j < 4; j++) {
                float s, c;
                sincosf((TWO_PI / 4096.0f) * (float)(b * (d0 + j)), &s, &c);
                orv[j] = ar[j][i] * c - ai[j][i] * s;
                oiv[j] = ar[j][i] * s + ai[j][i] * c;
            }
            *(float4*)&Gr[b * GS + d0] = make_float4(orv[0], orv[1], orv[2], orv[3]);
            *(float4*)&Gi[b * GS + d0] = make_float4(oiv[0], oiv[1], oiv[2], oiv[3]);
        }
    }
    __syncthreads();

    // ---------------- stage 2 (STEP2, proven) -> h in registers ----------
    float hv[4][2];
    int   dl_, cg_;
    {
        const int dl = (t & 31) * 2;
        const int cg = t >> 5;                     // 0..7
        dl_ = dl; cg_ = cg;
        float swi_, swr_; sincosf((TWO_PI / 64.0f) * (float)cg, &swi_, &swr_);
        const float swr = swr_, swi = swi_;        // step e^{2pi i cg/64}
        float rr = 1.0f, ri = 0.0f;
        float acc00 = 0, acc01 = 0, acc10 = 0, acc11 = 0;
        float acc20 = 0, acc21 = 0, acc30 = 0, acc31 = 0;
        int bb = 0;

#define S2C 0.70710678118654752f
#define STEP2(f8r, f8i, f16r, f16i, f24r, f24i)                                \
        {                                                                      \
            const float2 g_r = *(const float2*)&Gr[bb * GS + dl];              \
            const float2 g_i = *(const float2*)&Gi[bb * GS + dl];              \
            acc00 += g_r.x * rr - g_i.x * ri;                                  \
            acc01 += g_r.y * rr - g_i.y * ri;                                  \
            { const float tr = rr*(f8r) - ri*(f8i), ti = rr*(f8i) + ri*(f8r);  \
              acc10 += g_r.x * tr - g_i.x * ti;                                \
              acc11 += g_r.y * tr - g_i.y * ti; }                              \
            { const float tr = rr*(f16r) - ri*(f16i), ti = rr*(f16i) + ri*(f16r); \
              acc20 += g_r.x * tr - g_i.x * ti;                                \
              acc21 += g_r.y * tr - g_i.y * ti; }                              \
            { const float tr = rr*(f24r) - ri*(f24i), ti = rr*(f24i) + ri*(f24r); \
              acc30 += g_r.x * tr - g_i.x * ti;                                \
              acc31 += g_r.y * tr - g_i.y * ti; }                              \
            { const float nr = rr * swr - ri * swi;                            \
              const float ni = rr * swi + ri * swr;                            \
              rr = nr; ri = ni; }                                              \
            bb++;                                                              \
        }

        for (int grp = 0; grp < 8; grp++) {
            STEP2( 1.0f, 0.0f,   1.0f, 0.0f,   1.0f, 0.0f)
            STEP2( S2C,  S2C,    0.0f, 1.0f,  -S2C,  S2C)
            STEP2( 0.0f, 1.0f,  -1.0f, 0.0f,   0.0f,-1.0f)
            STEP2(-S2C,  S2C,    0.0f,-1.0f,   S2C,  S2C)
            STEP2(-1.0f, 0.0f,   1.0f, 0.0f,  -1.0f, 0.0f)
            STEP2(-S2C, -S2C,    0.0f, 1.0f,   S2C, -S2C)
            STEP2( 0.0f,-1.0f,  -1.0f, 0.0f,   0.0f, 1.0f)
            STEP2( S2C, -S2C,    0.0f,-1.0f,  -S2C, -S2C)
        }
#undef STEP2
        const float sc = 1.0f / 4096.0f;
        hv[0][0] = acc00 * sc; hv[0][1] = acc01 * sc;
        hv[1][0] = acc10 * sc; hv[1][1] = acc11 * sc;
        hv[2][0] = acc20 * sc; hv[2][1] = acc21 * sc;
        hv[3][0] = acc30 * sc; hv[3][1] = acc31 * sc;
    }
    __syncthreads();   // all G reads done; U is free

    // ---------------- h -> LDS ----------------
    #pragma unroll
    for (int v = 0; v < 4; v++) {
        const int c = cg_ + 8 * v;
        const int n = 64 * c + dl_;
        if (n < IR_LEN)     hU[n]     = hv[v][0];
        if (n + 1 < IR_LEN) hU[n + 1] = hv[v][1];
    }
    __syncthreads();

    // ---------------- FIR: z[o], o in [0,160) ----------------
    if (t < 240) {
        const int o0 = (t % 20) * 8;
        const int kc = t / 20;                 // 0..11
        const int kb = kc * 168;
        const int ns = (kc == 11) ? 38 : 42;   // 11*168=1848, +152 = 2000
        float s0[8] = {0,0,0,0,0,0,0,0};
        int Bo = o0 + 1996 - kb;               // mult of 4, >= 0
        float4 w1 = *(const float4*)&xws[XPHYS(Bo + 4)];
        float4 w2 = *(const float4*)&xws[XPHYS(Bo + 8)];
        for (int s = 0; s < ns; s++) {
            const float4 w0 = *(const float4*)&xws[XPHYS(Bo)];
            const float4 ha = *(const float4*)&hU[kb + 4 * s];
            const float wv[12] = {w0.x, w0.y, w0.z, w0.w,
                                  w1.x, w1.y, w1.z, w1.w,
                                  w2.x, w2.y, w2.z, w2.w};
            const float hav[4] = {ha.x, ha.y, ha.z, ha.w};
            #pragma unroll
            for (int jo = 0; jo < 8; jo++) {
                #pragma unroll
                for (int jk = 0; jk < 4; jk++) {
                    s0[jo] += hav[jk] * wv[3 + jo - jk];
                }
            }
            w2 = w1; w1 = w0; Bo -= 4;
        }
        const int rb = kc * 168 + o0;          // stride 168 (8 mod 32): spread
        *(float4*)&red[rb]     = make_float4(s0[0], s0[1], s0[2], s0[3]);
        *(float4*)&red[rb + 4] = make_float4(s0[4], s0[5], s0[6], s0[7]);
    }
    __syncthreads();

    // ---------------- epilogue: tent-weighted atomic scatter ----------------
    if (t < 160) {
        float z = 0.0f;
        #pragma unroll
        for (int kc = 0; kc < 12; kc++) z += red[kc * 168 + t];
        const int o = t;
        const int tout = t0 - PFRAME + o;
        float wgt = (o < PFRAME) ? (float)o * (1.0f / PFRAME)
                                 : (float)(160 - o) * (1.0f / PFRAME);
        if (frame == NFRAMES - 1 && o >= PFRAME) wgt = 1.0f;  // clamped h_next
        if (tout >= 0) {                       // frame 0 has no previous frame
            atomicAdd(&y[batch * T_TOTAL + tout], wgt * z);
        }
    }
}

extern "C" void kernel_launch(void* const* d_in, const int* in_sizes, int n_in,
                              void* d_out, int out_size, void* d_ws, size_t ws_size,
                              hipStream_t stream) {
    const float* x  = (const float*)d_in[0];   // (2, 24000)
    const float* mc = (const float*)d_in[1];   // (2, 300, 25)
    float* y = (float*)d_out;                  // (2, 24000)

    hipMemsetAsync(y, 0, (size_t)out_size * sizeof(float), stream);
    minphase_fir_fused<<<NROWS, 256, 0, stream>>>(mc, x, y);
}

// Round 10
// 100.861 us; speedup vs baseline: 4.4947x; 1.1074x over previous
//
#include <hip/hip_runtime.h>
#include <math.h>

#define IR_LEN  2000
#define PFRAME  80
#define NFRAMES 300
#define NBATCH  2
#define NROWS   (NBATCH*NFRAMES)     // 600
#define T_TOTAL (NFRAMES*PFRAME)     // 24000
#define NCOEF   25
#define TWO_PI  6.283185307179586f
#define GS      68                   // G row stride in floats (16B-aligned rows)
#define XWN     2160                 // logical x-window floats per block
#define XWPAD   2432                 // physical (4-float pad per 32): 2160+4*68

#define XPHYS(B) ((B) + (((B) >> 5) << 2))

// ---------------------------------------------------------------------------
// Fully fused kernel: one block per (batch,frame) row. 600 blocks, 256 thr.
//   stage x : x window -> LDS (padded), first, to hide HBM latency.
//   phase E : E[f] = exp(sum_k c[k] e^{-2pi i f k/4096}) -> LDS SoA + mirror.
//             Per-thread base rotation chained by const e^{-i pi/8} across the
//             8 f's (1 sincosf instead of 8).
//   stage 1 : RADIX-2 over a:  G[b][d]    = Te[d] + w64^d To[d],
//                              G[b][d+32] = Te[d] - w64^d To[d],
//             Te/To = sum_{a2<32} E[128a2(+64)+b] w32^{a2 d} — one shared
//             rotation chain per d. Thread = 4b x 2d (16 pts, 144 FMA/pt vs
//             320 direct). Then G' = G e^{2pi i bd/4096} -> same layout as R9.
//   stage 2 : h[64c+d] = (1/4096) Re sum_b G'[b][d] w64^{bc} (STEP2, proven).
//   FIR     : z[o] = <h, xwin(t0-80+o)>, o in [0,160) (R9 proven tile).
//   epilogue: y[t0-80+o] += tent(o) * z[o] via atomicAdd (y pre-zeroed).
// LDS: 34.8 KB union + 9.7 KB xw + csh ~= 45 KB -> 3 blocks/CU (= grid need).
// No reg-capping launch bounds (R6 lesson: capping -> scratch spills).
// ---------------------------------------------------------------------------
__global__ __launch_bounds__(256) void minphase_fir_fused(
        const float* __restrict__ mc, const float* __restrict__ x,
        float* __restrict__ y) {
    __shared__ __align__(16) float U[8704];    // 34.8 KB union
    __shared__ __align__(16) float xws[XWPAD]; // 9.7 KB padded x window
    __shared__ float csh[NCOEF];
    float* const EHr = U;                      // [4096]      (phase E)
    float* const EHi = U + 4096;               // [4096]
    float* const Gr  = U;                      // [64*GS]     (stages 1/2)
    float* const Gi  = U + 4352;               // [64*GS]
    float* const hU  = U;                      // [2000]      (FIR phase)
    float* const red = U + 4224;               // [12 rows, stride 168]

    const int row   = blockIdx.x;
    const int batch = row / NFRAMES;
    const int frame = row - batch * NFRAMES;
    const int t0    = frame * PFRAME;
    const int t     = threadIdx.x;

    if (t < NCOEF) csh[t] = mc[row * NCOEF + t];

    // ---------------- stage x: pre-stage x window (padded) ----------------
    {
        const float* xb = x + batch * T_TOTAL;
        for (int j = t; j < XWN; j += 256) {
            const int xi = t0 - 2079 + j;
            const float v = (xi >= 0 && xi < T_TOTAL) ? xb[xi] : 0.0f;
            xws[XPHYS(j)] = v;
        }
    }
    __syncthreads();

    // ---------------- phase E (conjugate mirror, chained base) ------------
    {
        float bs, bc; sincosf(-(TWO_PI / 4096.0f) * (float)t, &bs, &bc);
        const float SC =  0.923879532511287f;   // cos(pi/8)
        const float SS = -0.382683432365090f;   // sin(-pi/8)
        #pragma unroll 4
        for (int ii = 0; ii < 8; ii++) {
            const int f = t + 256 * ii;                // 0..2047
            const float wc = bc, ws = bs;              // e^{-2pi i f/4096}
            { const float nr = bc * SC - bs * SS;      // advance base
              const float ni = bc * SS + bs * SC;
              bc = nr; bs = ni; }
            float cr = 1.0f, ci = 0.0f, Cr = 0.0f, Ci = 0.0f;
            #pragma unroll
            for (int k = 0; k < NCOEF; k++) {
                const float cc = csh[k];
                Cr += cc * cr; Ci += cc * ci;
                const float nr = cr * wc - ci * ws;
                const float ni = cr * ws + ci * wc;
                cr = nr; ci = ni;
            }
            const float m = expf(Cr);
            float si, co; sincosf(Ci, &si, &co);
            const float er = m * co, ei = m * si;
            EHr[f] = er; EHi[f] = ei;
            if (f > 0) { EHr[4096 - f] = er; EHi[4096 - f] = -ei; }
        }
        if (t == 0) {                                  // f = 2048
            float Cr = 0.0f, Ci = 0.0f;
            float cr = 1.0f, ci = 0.0f;
            #pragma unroll
            for (int k = 0; k < NCOEF; k++) {
                Cr += csh[k] * cr; Ci += csh[k] * ci;
                cr = -cr; ci = -ci;                    // e^{-i pi k} = (-1)^k
            }
            const float m = expf(Cr);
            float si, co; sincosf(Ci, &si, &co);
            EHr[2048] = m * co; EHi[2048] = m * si;
        }
    }
    __syncthreads();

    // ---------------- stage 1 (radix-2 over a: 4b x 2d, Te/To) ------------
    {
        const int b0 = (t & 15) * 4;
        const int d0 = (t >> 4) * 2;           // 0,2,...,30
        float Ter[2][4], Tei[2][4], Tor[2][4], Toi[2][4];
        #pragma unroll
        for (int j = 0; j < 2; j++)
            #pragma unroll
            for (int i = 0; i < 4; i++) {
                Ter[j][i] = 0.0f; Tei[j][i] = 0.0f;
                Tor[j][i] = 0.0f; Toi[j][i] = 0.0f;
            }
        float rr[2], ri[2], wr[2], wi[2];
        #pragma unroll
        for (int j = 0; j < 2; j++) {
            float s, c; sincosf((TWO_PI / 32.0f) * (float)(d0 + j), &s, &c);
            wr[j] = c; wi[j] = s; rr[j] = 1.0f; ri[j] = 0.0f;
        }
        #pragma unroll 2
        for (int a2 = 0; a2 < 32; a2++) {
            const float4 vre = *(const float4*)&EHr[128 * a2 + b0];
            const float4 vie = *(const float4*)&EHi[128 * a2 + b0];
            const float4 vro = *(const float4*)&EHr[128 * a2 + 64 + b0];
            const float4 vio = *(const float4*)&EHi[128 * a2 + 64 + b0];
            const float ere[4] = {vre.x, vre.y, vre.z, vre.w};
            const float eie[4] = {vie.x, vie.y, vie.z, vie.w};
            const float ero[4] = {vro.x, vro.y, vro.z, vro.w};
            const float eio[4] = {vio.x, vio.y, vio.z, vio.w};
            #pragma unroll
            for (int j = 0; j < 2; j++) {
                #pragma unroll
                for (int i = 0; i < 4; i++) {
                    Ter[j][i] += ere[i] * rr[j] - eie[i] * ri[j];
                    Tei[j][i] += ere[i] * ri[j] + eie[i] * rr[j];
                    Tor[j][i] += ero[i] * rr[j] - eio[i] * ri[j];
                    Toi[j][i] += ero[i] * ri[j] + eio[i] * rr[j];
                }
                const float nr = rr[j] * wr[j] - ri[j] * wi[j];
                const float ni = rr[j] * wi[j] + ri[j] * wr[j];
                rr[j] = nr; ri[j] = ni;
            }
        }
        __syncthreads();   // ALL E reads complete before G' overwrites U

        // combine (radix-2 butterfly) + bd/4096 twiddle + store
        float os[2], oc[2];
        #pragma unroll
        for (int j = 0; j < 2; j++)
            sincosf((TWO_PI / 64.0f) * (float)(d0 + j), &os[j], &oc[j]);
        #pragma unroll
        for (int i = 0; i < 4; i++) {
            const int b = b0 + i;
            float gpr[2], gpi[2], gmr[2], gmi[2];
            #pragma unroll
            for (int j = 0; j < 2; j++) {
                const int d = d0 + j;
                const float ur = oc[j] * Tor[j][i] - os[j] * Toi[j][i];
                const float ui = oc[j] * Toi[j][i] + os[j] * Tor[j][i];
                const float pr = Ter[j][i] + ur, pi = Tei[j][i] + ui;
                const float mr = Ter[j][i] - ur, mi = Tei[j][i] - ui;
                float s, c;
                sincosf((TWO_PI / 4096.0f) * (float)(b * d), &s, &c);
                gpr[j] = pr * c - pi * s; gpi[j] = pr * s + pi * c;
                sincosf((TWO_PI / 4096.0f) * (float)(b * (d + 32)), &s, &c);
                gmr[j] = mr * c - mi * s; gmi[j] = mr * s + mi * c;
            }
            *(float2*)&Gr[b * GS + d0]      = make_float2(gpr[0], gpr[1]);
            *(float2*)&Gi[b * GS + d0]      = make_float2(gpi[0], gpi[1]);
            *(float2*)&Gr[b * GS + d0 + 32] = make_float2(gmr[0], gmr[1]);
            *(float2*)&Gi[b * GS + d0 + 32] = make_float2(gmi[0], gmi[1]);
        }
    }
    __syncthreads();

    // ---------------- stage 2 (STEP2, proven) -> h in registers ----------
    float hv[4][2];
    int   dl_, cg_;
    {
        const int dl = (t & 31) * 2;
        const int cg = t >> 5;                     // 0..7
        dl_ = dl; cg_ = cg;
        float swi_, swr_; sincosf((TWO_PI / 64.0f) * (float)cg, &swi_, &swr_);
        const float swr = swr_, swi = swi_;        // step e^{2pi i cg/64}
        float rr = 1.0f, ri = 0.0f;
        float acc00 = 0, acc01 = 0, acc10 = 0, acc11 = 0;
        float acc20 = 0, acc21 = 0, acc30 = 0, acc31 = 0;
        int bb = 0;

#define S2C 0.70710678118654752f
#define STEP2(f8r, f8i, f16r, f16i, f24r, f24i)                                \
        {                                                                      \
            const float2 g_r = *(const float2*)&Gr[bb * GS + dl];              \
            const float2 g_i = *(const float2*)&Gi[bb * GS + dl];              \
            acc00 += g_r.x * rr - g_i.x * ri;                                  \
            acc01 += g_r.y * rr - g_i.y * ri;                                  \
            { const float tr = rr*(f8r) - ri*(f8i), ti = rr*(f8i) + ri*(f8r);  \
              acc10 += g_r.x * tr - g_i.x * ti;                                \
              acc11 += g_r.y * tr - g_i.y * ti; }                              \
            { const float tr = rr*(f16r) - ri*(f16i), ti = rr*(f16i) + ri*(f16r); \
              acc20 += g_r.x * tr - g_i.x * ti;                                \
              acc21 += g_r.y * tr - g_i.y * ti; }                              \
            { const float tr = rr*(f24r) - ri*(f24i), ti = rr*(f24i) + ri*(f24r); \
              acc30 += g_r.x * tr - g_i.x * ti;                                \
              acc31 += g_r.y * tr - g_i.y * ti; }                              \
            { const float nr = rr * swr - ri * swi;                            \
              const float ni = rr * swi + ri * swr;                            \
              rr = nr; ri = ni; }                                              \
            bb++;                                                              \
        }

        for (int grp = 0; grp < 8; grp++) {
            STEP2( 1.0f, 0.0f,   1.0f, 0.0f,   1.0f, 0.0f)
            STEP2( S2C,  S2C,    0.0f, 1.0f,  -S2C,  S2C)
            STEP2( 0.0f, 1.0f,  -1.0f, 0.0f,   0.0f,-1.0f)
            STEP2(-S2C,  S2C,    0.0f,-1.0f,   S2C,  S2C)
            STEP2(-1.0f, 0.0f,   1.0f, 0.0f,  -1.0f, 0.0f)
            STEP2(-S2C, -S2C,    0.0f, 1.0f,   S2C, -S2C)
            STEP2( 0.0f,-1.0f,  -1.0f, 0.0f,   0.0f, 1.0f)
            STEP2( S2C, -S2C,    0.0f,-1.0f,  -S2C, -S2C)
        }
#undef STEP2
        const float sc = 1.0f / 4096.0f;
        hv[0][0] = acc00 * sc; hv[0][1] = acc01 * sc;
        hv[1][0] = acc10 * sc; hv[1][1] = acc11 * sc;
        hv[2][0] = acc20 * sc; hv[2][1] = acc21 * sc;
        hv[3][0] = acc30 * sc; hv[3][1] = acc31 * sc;
    }
    __syncthreads();   // all G reads done; U is free

    // ---------------- h -> LDS ----------------
    #pragma unroll
    for (int v = 0; v < 4; v++) {
        const int c = cg_ + 8 * v;
        const int n = 64 * c + dl_;
        if (n < IR_LEN)     hU[n]     = hv[v][0];
        if (n + 1 < IR_LEN) hU[n + 1] = hv[v][1];
    }
    __syncthreads();

    // ---------------- FIR: z[o], o in [0,160) ----------------
    if (t < 240) {
        const int o0 = (t % 20) * 8;
        const int kc = t / 20;                 // 0..11
        const int kb = kc * 168;
        const int ns = (kc == 11) ? 38 : 42;   // 11*168=1848, +152 = 2000
        float s0[8] = {0,0,0,0,0,0,0,0};
        int Bo = o0 + 1996 - kb;               // mult of 4, >= 0
        float4 w1 = *(const float4*)&xws[XPHYS(Bo + 4)];
        float4 w2 = *(const float4*)&xws[XPHYS(Bo + 8)];
        for (int s = 0; s < ns; s++) {
            const float4 w0 = *(const float4*)&xws[XPHYS(Bo)];
            const float4 ha = *(const float4*)&hU[kb + 4 * s];
            const float wv[12] = {w0.x, w0.y, w0.z, w0.w,
                                  w1.x, w1.y, w1.z, w1.w,
                                  w2.x, w2.y, w2.z, w2.w};
            const float hav[4] = {ha.x, ha.y, ha.z, ha.w};
            #pragma unroll
            for (int jo = 0; jo < 8; jo++) {
                #pragma unroll
                for (int jk = 0; jk < 4; jk++) {
                    s0[jo] += hav[jk] * wv[3 + jo - jk];
                }
            }
            w2 = w1; w1 = w0; Bo -= 4;
        }
        const int rb = kc * 168 + o0;
        *(float4*)&red[rb]     = make_float4(s0[0], s0[1], s0[2], s0[3]);
        *(float4*)&red[rb + 4] = make_float4(s0[4], s0[5], s0[6], s0[7]);
    }
    __syncthreads();

    // ---------------- epilogue: tent-weighted atomic scatter ----------------
    if (t < 160) {
        float z = 0.0f;
        #pragma unroll
        for (int kc = 0; kc < 12; kc++) z += red[kc * 168 + t];
        const int o = t;
        const int tout = t0 - PFRAME + o;
        float wgt = (o < PFRAME) ? (float)o * (1.0f / PFRAME)
                                 : (float)(160 - o) * (1.0f / PFRAME);
        if (frame == NFRAMES - 1 && o >= PFRAME) wgt = 1.0f;  // clamped h_next
        if (tout >= 0) {                       // frame 0 has no previous frame
            atomicAdd(&y[batch * T_TOTAL + tout], wgt * z);
        }
    }
}

extern "C" void kernel_launch(void* const* d_in, const int* in_sizes, int n_in,
                              void* d_out, int out_size, void* d_ws, size_t ws_size,
                              hipStream_t stream) {
    const float* x  = (const float*)d_in[0];   // (2, 24000)
    const float* mc = (const float*)d_in[1];   // (2, 300, 25)
    float* y = (float*)d_out;                  // (2, 24000)

    hipMemsetAsync(y, 0, (size_t)out_size * sizeof(float), stream);
    minphase_fir_fused<<<NROWS, 256, 0, stream>>>(mc, x, y);
}